// Round 12
// baseline (689.186 us; speedup 1.0000x reference)
//
#include <hip/hip_runtime.h>
#include <stdint.h>

// GeneDynamics: out = -x + (A @ x^2) / (x^2 + 1)
// v8: reg-staged (T14) pipeline. Every A global load = 1 KiB fully-contiguous
//     wave burst (global_load_dwordx4, KC=256). No global_load_lds (avoids
//     compiler vmcnt-drain before aliasing ds_reads). Raw s_barrier + own
//     counted waits (m201 pattern). 64x256 tile + xh chunk = 80 KiB -> 2 blk/CU.

#define NN 16384
#define DIM 16
#define TPB 256                // 4 waves
#define ROWS 64                // rows per block
#define NRB 256                // NN / ROWS
#define KSPLIT 2
#define KRANGE 8192            // NN / KSPLIT
#define KC 256                 // k per chunk (1 KiB per row per chunk)
#define NCH 32                 // KRANGE / KC

// prep: out = -x ; xh = x^2 ; inv = 1/(x^2+1)
__global__ __launch_bounds__(256) void prep_kernel(const float* __restrict__ x,
                                                   float* __restrict__ out,
                                                   float* __restrict__ xh,
                                                   float* __restrict__ inv) {
    int i = blockIdx.x * 256 + threadIdx.x;            // 65536 float4s
    float4 v = reinterpret_cast<const float4*>(x)[i];
    reinterpret_cast<float4*>(out)[i] = make_float4(-v.x, -v.y, -v.z, -v.w);
    float4 h = make_float4(v.x * v.x, v.y * v.y, v.z * v.z, v.w * v.w);
    reinterpret_cast<float4*>(xh)[i] = h;
    reinterpret_cast<float4*>(inv)[i] =
        make_float4(1.0f / (h.x + 1.0f), 1.0f / (h.y + 1.0f),
                    1.0f / (h.z + 1.0f), 1.0f / (h.w + 1.0f));
}

__global__ __launch_bounds__(TPB, 2) void agg_kernel(const float* __restrict__ A,
                                                     const float* __restrict__ xh,
                                                     const float* __restrict__ inv,
                                                     float* __restrict__ out) {
    // tA[row][256 k]: row r stores logical f4-slot s at phys s^(r&7) (involution).
    // tX[256 k][16 d]: k's d-f4-slot v stored at v^((k>>4)&3).
    __shared__ float tA[ROWS * KC];   // 64 KiB
    __shared__ float tX[KC * DIM];    // 16 KiB

    const int tid = threadIdx.x;
    const int l = tid & 63, w = tid >> 6, m = l & 15, q = l >> 4;
    const int rb = blockIdx.x & (NRB - 1);
    const int ks = blockIdx.x >> 8;
    const int r0 = rb * ROWS;
    const size_t k0 = (size_t)ks * KRANGE;

    // ---- global staging bases: wave w stages rows [16w,16w+16) of the tile;
    //      instr i: lane l reads bytes l*16 of row(16w+i)'s 1 KiB chunk-segment.
    const float* Ab = A + (size_t)(r0 + 16 * w) * NN + k0 + 4 * l;
    //      xh chunk (16 KiB contiguous): instr i covers floats [(4w+i)*256,+256)
    const float* Xb = xh + k0 * DIM + (4 * w) * 256 + 4 * l;

    // ---- LDS write indices (loop-invariant, float units) ----
    int wAi[16], wXi[4];
    #pragma unroll
    for (int i = 0; i < 16; ++i)
        wAi[i] = (16 * w + i) * KC + 4 * (l ^ (i & 7));   // (16w+i)&7 == i&7
    #pragma unroll
    for (int i = 0; i < 4; ++i) {
        int p = (4 * w + i) * 64 + l;                     // logical f4-slot
        wXi[i] = 4 * (p ^ ((p >> 6) & 3));                // flips v-bits by (k>>4)&3
    }

    // ---- LDS read indices (loop-invariant) ----
    // lane (m,q): rows {m+16j}, k-slots {16w+4q+b}
    int rA[4][4];
    #pragma unroll
    for (int j = 0; j < 4; ++j)
        #pragma unroll
        for (int b = 0; b < 4; ++b)
            rA[j][b] = (m + 16 * j) * KC + 4 * ((16 * w + 4 * q + b) ^ (m & 7));
    const int swz = (4 * w + q) & 3;                      // (k_loc>>4)&3 for this lane
    int rX[4];
    #pragma unroll
    for (int v = 0; v < 4; ++v)
        rX[v] = (64 * w + 16 * q) * 16 + 4 * (v ^ swz);

    float4 acc[4][4];   // [row j][d-slot v]
    #pragma unroll
    for (int j = 0; j < 4; ++j)
        #pragma unroll
        for (int v = 0; v < 4; ++v) acc[j][v] = make_float4(0.f, 0.f, 0.f, 0.f);

    float4 ra[16], rx[4];   // staging register bank (chunk t)

    // ---- prologue: load chunk 0 into regs ----
    #pragma unroll
    for (int i = 0; i < 16; ++i)
        ra[i] = *reinterpret_cast<const float4*>(Ab + (size_t)i * NN);
    #pragma unroll
    for (int i = 0; i < 4; ++i)
        rx[i] = *reinterpret_cast<const float4*>(Xb + i * 256);

    for (int t = 0; t < NCH; ++t) {
        asm volatile("s_waitcnt vmcnt(0)" ::: "memory");  // chunk t regs arrived
        __builtin_amdgcn_sched_barrier(0);
        __builtin_amdgcn_s_barrier();                     // all waves done reading tile t-1
        // ---- commit chunk t to LDS (contiguous 1 KiB per instr, conflict-free) ----
        #pragma unroll
        for (int i = 0; i < 16; ++i)
            *reinterpret_cast<float4*>(&tA[wAi[i]]) = ra[i];
        #pragma unroll
        for (int i = 0; i < 4; ++i)
            *reinterpret_cast<float4*>(&tX[wXi[i]]) = rx[i];
        asm volatile("s_waitcnt lgkmcnt(0)" ::: "memory"); // writes retired; regs reusable
        __builtin_amdgcn_sched_barrier(0);
        __builtin_amdgcn_s_barrier();                      // tile t complete
        if (t + 1 < NCH) {
            // ---- issue chunk t+1 loads (in flight across the whole compute) ----
            const float* An = Ab + (size_t)(t + 1) * KC;
            const float* Xn = Xb + (size_t)(t + 1) * (KC * DIM);
            #pragma unroll
            for (int i = 0; i < 16; ++i)
                ra[i] = *reinterpret_cast<const float4*>(An + (size_t)i * NN);
            #pragma unroll
            for (int i = 0; i < 4; ++i)
                rx[i] = *reinterpret_cast<const float4*>(Xn + i * 256);
            __builtin_amdgcn_sched_barrier(0);             // pin issue before compute
        }
        // ---- compute chunk t: LDS-only reads + FMA ----
        #pragma unroll
        for (int b = 0; b < 4; ++b) {
            float4 ar[4];
            #pragma unroll
            for (int j = 0; j < 4; ++j)
                ar[j] = *reinterpret_cast<const float4*>(&tA[rA[j][b]]);
            #pragma unroll
            for (int e = 0; e < 4; ++e) {
                float4 xv[4];
                #pragma unroll
                for (int v = 0; v < 4; ++v)
                    xv[v] = *reinterpret_cast<const float4*>(
                        &tX[rX[v] + (4 * b + e) * 16]);
                #pragma unroll
                for (int j = 0; j < 4; ++j) {
                    const float a = (&ar[j].x)[e];         // e unrolled -> static
                    #pragma unroll
                    for (int v = 0; v < 4; ++v) {
                        acc[j][v].x += a * xv[v].x;
                        acc[j][v].y += a * xv[v].y;
                        acc[j][v].z += a * xv[v].z;
                        acc[j][v].w += a * xv[v].w;
                    }
                }
            }
        }
    }

    // ---- merge the 4 k-phases q (lane bits 4,5) ----
    #pragma unroll
    for (int j = 0; j < 4; ++j)
        #pragma unroll
        for (int v = 0; v < 4; ++v) {
            acc[j][v].x += __shfl_xor(acc[j][v].x, 16);
            acc[j][v].y += __shfl_xor(acc[j][v].y, 16);
            acc[j][v].z += __shfl_xor(acc[j][v].z, 16);
            acc[j][v].w += __shfl_xor(acc[j][v].w, 16);
            acc[j][v].x += __shfl_xor(acc[j][v].x, 32);
            acc[j][v].y += __shfl_xor(acc[j][v].y, 32);
            acc[j][v].z += __shfl_xor(acc[j][v].z, 32);
            acc[j][v].w += __shfl_xor(acc[j][v].w, 32);
        }

    // q==0 lanes write rows m+16j; all waves + KSPLIT merge via atomics
    // (epilogue is linear in agg -> split-K exact)
    if (q == 0) {
        #pragma unroll
        for (int j = 0; j < 4; ++j) {
            const int R = r0 + m + 16 * j;
            const float4* iv4 = reinterpret_cast<const float4*>(inv + (size_t)R * DIM);
            float* orow = out + (size_t)R * DIM;
            #pragma unroll
            for (int v = 0; v < 4; ++v) {
                float4 iv = iv4[v];
                atomicAdd(&orow[4 * v + 0], acc[j][v].x * iv.x);
                atomicAdd(&orow[4 * v + 1], acc[j][v].y * iv.y);
                atomicAdd(&orow[4 * v + 2], acc[j][v].z * iv.z);
                atomicAdd(&orow[4 * v + 3], acc[j][v].w * iv.w);
            }
        }
    }
}

extern "C" void kernel_launch(void* const* d_in, const int* in_sizes, int n_in,
                              void* d_out, int out_size, void* d_ws, size_t ws_size,
                              hipStream_t stream) {
    const float* A = (const float*)d_in[0];
    const float* x = (const float*)d_in[1];
    float* out = (float*)d_out;
    float* xhp = (float*)d_ws;                      // 1 MiB
    float* inv = (float*)d_ws + (size_t)NN * DIM;   // 1 MiB

    prep_kernel<<<(NN * DIM / 4) / 256, 256, 0, stream>>>(x, out, xhp, inv);
    agg_kernel<<<NRB * KSPLIT, TPB, 0, stream>>>(A, xhp, inv, out);
}

// Round 13
// 382.404 us; speedup vs baseline: 1.8022x; 1.8022x over previous
//
#include <hip/hip_runtime.h>
#include <stdint.h>

// GeneDynamics: out = -x + (A @ x^2) / (x^2 + 1)
// v9: v8 burst geometry (KC=256 -> each staging instr = ONE row's 1 KiB
//     fully-contiguous segment) but via global_load_lds: zero staging regs,
//     zero spills. Single 80 KiB buffer, 2 blocks/CU, plain 2-phase
//     __syncthreads pipeline (co-resident block covers the drain).

#define NN 16384
#define DIM 16
#define TPB 256                // 4 waves
#define ROWS 64                // rows per block
#define NRB 256                // NN / ROWS
#define KSPLIT 2
#define KRANGE 8192            // NN / KSPLIT
#define KC 256                 // k per chunk (1 KiB per row per chunk)
#define NCH 32                 // KRANGE / KC

// prep: out = -x ; xh = x^2 ; inv = 1/(x^2+1)
__global__ __launch_bounds__(256) void prep_kernel(const float* __restrict__ x,
                                                   float* __restrict__ out,
                                                   float* __restrict__ xh,
                                                   float* __restrict__ inv) {
    int i = blockIdx.x * 256 + threadIdx.x;            // 65536 float4s
    float4 v = reinterpret_cast<const float4*>(x)[i];
    reinterpret_cast<float4*>(out)[i] = make_float4(-v.x, -v.y, -v.z, -v.w);
    float4 h = make_float4(v.x * v.x, v.y * v.y, v.z * v.z, v.w * v.w);
    reinterpret_cast<float4*>(xh)[i] = h;
    reinterpret_cast<float4*>(inv)[i] =
        make_float4(1.0f / (h.x + 1.0f), 1.0f / (h.y + 1.0f),
                    1.0f / (h.z + 1.0f), 1.0f / (h.w + 1.0f));
}

__device__ __forceinline__ void gload_lds16(const float* g, float* l) {
    __builtin_amdgcn_global_load_lds(
        (const __attribute__((address_space(1))) void*)g,
        (__attribute__((address_space(3))) void*)l, 16, 0, 0);
}

__global__ __launch_bounds__(TPB) void agg_kernel(const float* __restrict__ A,
                                                  const float* __restrict__ xh,
                                                  const float* __restrict__ inv,
                                                  float* __restrict__ out) {
    // tA[row][256 k]: row r holds logical f4-slot s at phys s^(r&7) (involution,
    //   carried on the per-lane SOURCE address; LDS dest stays lane-linear).
    // tX[256 k][16 d]: k's d-f4-slot v stored at phys v^((k>>4)&3).
    __shared__ float tA[ROWS * KC];   // 64 KiB
    __shared__ float tX[KC * DIM];    // 16 KiB

    const int tid = threadIdx.x;
    const int l = tid & 63, w = tid >> 6, m = l & 15, q = l >> 4;
    const int rb = blockIdx.x & (NRB - 1);
    const int ks = blockIdx.x >> 8;
    const int r0 = rb * ROWS;
    const size_t k0 = (size_t)ks * KRANGE;

    // ---- A staging: wave w, instr i -> row 16w+i, lane l loads logical
    //      f4-slot l^(i&7) of that row's 1 KiB chunk segment (full contiguous span)
    const float* Ab = A + (size_t)(r0 + 16 * w) * NN + k0;
    int aoff[8];
    #pragma unroll
    for (int i = 0; i < 8; ++i) aoff[i] = 4 * (l ^ i);    // index by i&7

    // ---- X staging: instr j covers phys f4-slots (4w+j)*64 + l;
    //      k = (4w+j)*16 + (l>>2), phys v-slot = l&3 holds logical (l&3)^j
    const float* Xc = xh + k0 * DIM;
    int xoff[4];
    #pragma unroll
    for (int j = 0; j < 4; ++j)
        xoff[j] = (((4 * w + j) * 16 + (l >> 2)) << 4) + 4 * ((l & 3) ^ j);

    // ---- compute-side read indices (loop-invariant) ----
    // thread (w,q,m): rows m+16j, k_loc = 64w+16q+4b+e
    int rA[4][4];
    #pragma unroll
    for (int j = 0; j < 4; ++j)
        #pragma unroll
        for (int b = 0; b < 4; ++b)
            rA[j][b] = (m + 16 * j) * KC + 4 * ((16 * w + 4 * q + b) ^ (m & 7));
    int rX[4];
    #pragma unroll
    for (int v = 0; v < 4; ++v)
        rX[v] = (64 * w + 16 * q) * 16 + 4 * (v ^ q);

    float4 acc[4][4];   // [row j][d-slot v]
    #pragma unroll
    for (int j = 0; j < 4; ++j)
        #pragma unroll
        for (int v = 0; v < 4; ++v) acc[j][v] = make_float4(0.f, 0.f, 0.f, 0.f);

    for (int t = 0; t < NCH; ++t) {
        __syncthreads();                 // tile t-1 fully consumed by all waves
        // ---- STAGE(t): 16 A-instrs (1 KiB contiguous each) + 4 X-instrs ----
        {
            const float* sA = Ab + (size_t)t * KC;
            #pragma unroll
            for (int i = 0; i < 16; ++i)
                gload_lds16(sA + (size_t)i * NN + aoff[i & 7],
                            &tA[(16 * w + i) * KC]);
            const float* sX = Xc + (size_t)t * (KC * DIM);
            #pragma unroll
            for (int j = 0; j < 4; ++j)
                gload_lds16(sX + xoff[j], &tX[(4 * w + j) * 256]);
        }
        __syncthreads();                 // vmcnt(0) drain: tile t resident
        // ---- COMPUTE(t): LDS-only reads + FMA ----
        #pragma unroll
        for (int b = 0; b < 4; ++b) {
            float4 ar[4];
            #pragma unroll
            for (int j = 0; j < 4; ++j)
                ar[j] = *reinterpret_cast<const float4*>(&tA[rA[j][b]]);
            #pragma unroll
            for (int e = 0; e < 4; ++e) {
                float4 xv[4];
                #pragma unroll
                for (int v = 0; v < 4; ++v)
                    xv[v] = *reinterpret_cast<const float4*>(
                        &tX[rX[v] + (4 * b + e) * 16]);
                #pragma unroll
                for (int j = 0; j < 4; ++j) {
                    const float a = (&ar[j].x)[e];         // e unrolled -> static
                    #pragma unroll
                    for (int v = 0; v < 4; ++v) {
                        acc[j][v].x += a * xv[v].x;
                        acc[j][v].y += a * xv[v].y;
                        acc[j][v].z += a * xv[v].z;
                        acc[j][v].w += a * xv[v].w;
                    }
                }
            }
        }
    }

    // ---- merge the 4 k-phases q (lane bits 4,5) ----
    #pragma unroll
    for (int j = 0; j < 4; ++j)
        #pragma unroll
        for (int v = 0; v < 4; ++v) {
            acc[j][v].x += __shfl_xor(acc[j][v].x, 16);
            acc[j][v].y += __shfl_xor(acc[j][v].y, 16);
            acc[j][v].z += __shfl_xor(acc[j][v].z, 16);
            acc[j][v].w += __shfl_xor(acc[j][v].w, 16);
            acc[j][v].x += __shfl_xor(acc[j][v].x, 32);
            acc[j][v].y += __shfl_xor(acc[j][v].y, 32);
            acc[j][v].z += __shfl_xor(acc[j][v].z, 32);
            acc[j][v].w += __shfl_xor(acc[j][v].w, 32);
        }

    // q==0 lanes write rows m+16j; waves + KSPLIT merge via atomics
    // (epilogue is linear in agg -> split-K exact)
    if (q == 0) {
        #pragma unroll
        for (int j = 0; j < 4; ++j) {
            const int R = r0 + m + 16 * j;
            const float4* iv4 = reinterpret_cast<const float4*>(inv + (size_t)R * DIM);
            float* orow = out + (size_t)R * DIM;
            #pragma unroll
            for (int v = 0; v < 4; ++v) {
                float4 iv = iv4[v];
                atomicAdd(&orow[4 * v + 0], acc[j][v].x * iv.x);
                atomicAdd(&orow[4 * v + 1], acc[j][v].y * iv.y);
                atomicAdd(&orow[4 * v + 2], acc[j][v].z * iv.z);
                atomicAdd(&orow[4 * v + 3], acc[j][v].w * iv.w);
            }
        }
    }
}

extern "C" void kernel_launch(void* const* d_in, const int* in_sizes, int n_in,
                              void* d_out, int out_size, void* d_ws, size_t ws_size,
                              hipStream_t stream) {
    const float* A = (const float*)d_in[0];
    const float* x = (const float*)d_in[1];
    float* out = (float*)d_out;
    float* xhp = (float*)d_ws;                      // 1 MiB
    float* inv = (float*)d_ws + (size_t)NN * DIM;   // 1 MiB

    prep_kernel<<<(NN * DIM / 4) / 256, 256, 0, stream>>>(x, out, xhp, inv);
    agg_kernel<<<NRB * KSPLIT, TPB, 0, stream>>>(A, xhp, inv, out);
}